// Round 1
// baseline (311.960 us; speedup 1.0000x reference)
//
#include <hip/hip_runtime.h>
#include <cstdint>

#define NROWS 262144
#define DDIM 64
#define KCLUST 512
#define BM 32
#define THREADS 256
#define KC 256  // centroid cols per LDS chunk

typedef const __attribute__((address_space(1))) void* gas_ptr;
typedef __attribute__((address_space(3))) void* las_ptr;

__device__ __forceinline__ void g2lds16(const void* g, void* l) {
  // async global->LDS, 16B per lane; LDS dest must be wave-uniform base + lane*16
  __builtin_amdgcn_global_load_lds((gas_ptr)g, (las_ptr)l, 16, 0, 0);
}

// Precompute ||c_k||^2 for all K centroids into workspace.
__global__ void csq_kernel(const float* __restrict__ c, float* __restrict__ csq) {
  int k = blockIdx.x * blockDim.x + threadIdx.x;
  if (k < KCLUST) {
    const float4* cp = (const float4*)(c + k * DDIM);
    float s = 0.f;
#pragma unroll
    for (int i = 0; i < DDIM / 4; ++i) {
      float4 v = cp[i];
      s = fmaf(v.x, v.x, s);
      s = fmaf(v.y, v.y, s);
      s = fmaf(v.z, v.z, s);
      s = fmaf(v.w, v.w, s);
    }
    csq[k] = s;
  }
}

__global__ __launch_bounds__(THREADS) void cluster_kernel(
    const float* __restrict__ xg, const float* __restrict__ cg,
    const float* __restrict__ csq, float* __restrict__ outg) {
  __shared__ __align__(16) float sX[BM * DDIM];   // 8 KB
  __shared__ __align__(16) float sB[KC * DDIM];   // 64 KB, XOR-swizzled layout
  __shared__ float sX1[BM];                       // 1 + ||x_r||^2

  const int tid = threadIdx.x;
  const int lane = tid & 63;
  const int wv = tid >> 6;  // wave id = row group (8 rows each)
  const long rowBase = (long)blockIdx.x * BM;

  // ---- stage x tile (8 KB, linear) ----
  const char* gx = (const char*)(xg + rowBase * DDIM);
#pragma unroll
  for (int i = 0; i < (BM * DDIM * 4) / (THREADS * 16); ++i) {  // 2
    int p = (i * THREADS + tid) * 16;
    g2lds16(gx + p, (char*)sX + p);
  }

  // ---- stage centroid chunk 0 (64 KB), pre-swizzled global source ----
  // logical byte L = col*256 + d*4 ; physical P = L ^ ((col&7)<<4)
  const char* gc = (const char*)cg;
#pragma unroll
  for (int i = 0; i < (KC * DDIM * 4) / (THREADS * 16); ++i) {  // 16
    int p = (i * THREADS + tid) * 16;
    int lg = p ^ (((p >> 8) & 7) << 4);
    g2lds16(gc + lg, (char*)sB + p);
  }

  // ---- 1 + ||x_r||^2 from global (L2-hot), 32 threads ----
  if (tid < BM) {
    const float4* xr = (const float4*)(xg + (rowBase + tid) * DDIM);
    float s = 1.f;
#pragma unroll
    for (int i = 0; i < DDIM / 4; ++i) {
      float4 v = xr[i];
      s = fmaf(v.x, v.x, s);
      s = fmaf(v.y, v.y, s);
      s = fmaf(v.z, v.z, s);
      s = fmaf(v.w, v.w, s);
    }
    sX1[tid] = s;
  }

  // ---- per-thread ||c||^2 for its 8 columns (col = lane + 64*j) ----
  float c1[8];
#pragma unroll
  for (int j = 0; j < 8; ++j) c1[j] = csq[lane + 64 * j];

  float acc[8][8];
#pragma unroll
  for (int r = 0; r < 8; ++r)
#pragma unroll
    for (int j = 0; j < 8; ++j) acc[r][j] = 0.f;

  const int myx = (lane & 7) << 4;
  const char* bb = (const char*)sB + (lane << 8);  // col = lane row base
  const char* xb = (const char*)sX + (wv << 11);   // 8 rows * 256 B per wave

#pragma unroll
  for (int ch = 0; ch < 2; ++ch) {
    if (ch) {
      __syncthreads();  // all readers of previous chunk done
#pragma unroll
      for (int i = 0; i < (KC * DDIM * 4) / (THREADS * 16); ++i) {
        int p = (i * THREADS + tid) * 16;
        int lg = p ^ (((p >> 8) & 7) << 4);
        g2lds16(gc + KC * DDIM * 4 + lg, (char*)sB + p);
      }
    }
    __syncthreads();  // staged data visible (barrier drains vmcnt)

#pragma unroll 4
    for (int d4 = 0; d4 < DDIM / 4; ++d4) {
      const int boff = (d4 << 4) ^ myx;
      const int xoff = d4 << 4;
      float4 b0 = *(const float4*)(bb + 0 * 16384 + boff);
      float4 b1 = *(const float4*)(bb + 1 * 16384 + boff);
      float4 b2 = *(const float4*)(bb + 2 * 16384 + boff);
      float4 b3 = *(const float4*)(bb + 3 * 16384 + boff);
#pragma unroll
      for (int r = 0; r < 8; ++r) {
        float4 a = *(const float4*)(xb + r * 256 + xoff);  // broadcast read
        float t0 = acc[r][ch * 4 + 0];
        float t1 = acc[r][ch * 4 + 1];
        float t2 = acc[r][ch * 4 + 2];
        float t3 = acc[r][ch * 4 + 3];
        t0 = fmaf(a.x, b0.x, t0); t0 = fmaf(a.y, b0.y, t0);
        t0 = fmaf(a.z, b0.z, t0); t0 = fmaf(a.w, b0.w, t0);
        t1 = fmaf(a.x, b1.x, t1); t1 = fmaf(a.y, b1.y, t1);
        t1 = fmaf(a.z, b1.z, t1); t1 = fmaf(a.w, b1.w, t1);
        t2 = fmaf(a.x, b2.x, t2); t2 = fmaf(a.y, b2.y, t2);
        t2 = fmaf(a.z, b2.z, t2); t2 = fmaf(a.w, b2.w, t2);
        t3 = fmaf(a.x, b3.x, t3); t3 = fmaf(a.y, b3.y, t3);
        t3 = fmaf(a.z, b3.z, t3); t3 = fmaf(a.w, b3.w, t3);
        acc[r][ch * 4 + 0] = t0;
        acc[r][ch * 4 + 1] = t1;
        acc[r][ch * 4 + 2] = t2;
        acc[r][ch * 4 + 3] = t3;
      }
    }
  }

  // ---- epilogue: q = 1/(1+dist2), row-normalize, store ----
  const long orow0 = (rowBase + (long)wv * 8) * KCLUST;
#pragma unroll
  for (int r = 0; r < 8; ++r) {
    float x1 = sX1[wv * 8 + r];  // broadcast
    float q[8];
    float s = 0.f;
#pragma unroll
    for (int j = 0; j < 8; ++j) {
      // 1 + dist2 = (1 + xsq + csq) - 2*cross
      float t = fmaf(-2.f, acc[r][j], x1 + c1[j]);
      float qq = __builtin_amdgcn_rcpf(t);
      q[j] = qq;
      s += qq;
    }
#pragma unroll
    for (int m = 1; m < 64; m <<= 1) s += __shfl_xor(s, m, 64);
    float inv = __builtin_amdgcn_rcpf(s);
    float* op = outg + orow0 + (long)r * KCLUST + lane;
#pragma unroll
    for (int j = 0; j < 8; ++j) op[64 * j] = q[j] * inv;
  }
}

extern "C" void kernel_launch(void* const* d_in, const int* in_sizes, int n_in,
                              void* d_out, int out_size, void* d_ws, size_t ws_size,
                              hipStream_t stream) {
  const float* x = (const float*)d_in[0];
  const float* c = (const float*)d_in[1];
  float* out = (float*)d_out;
  float* csq = (float*)d_ws;  // 512 floats

  hipLaunchKernelGGL(csq_kernel, dim3(2), dim3(256), 0, stream, c, csq);
  hipLaunchKernelGGL(cluster_kernel, dim3(NROWS / BM), dim3(THREADS), 0, stream,
                     x, c, csq, out);
}

// Round 2
// 174.648 us; speedup vs baseline: 1.7862x; 1.7862x over previous
//
#include <hip/hip_runtime.h>
#include <cstdint>

#define NROWS 262144
#define DDIM 64
#define KCL 512
#define BM 32
#define THREADS 256

typedef __attribute__((ext_vector_type(8))) short short8;
typedef __attribute__((ext_vector_type(16))) float f32x16;
typedef const __attribute__((address_space(1))) void* gas_ptr;
typedef __attribute__((address_space(3))) void* las_ptr;

__device__ __forceinline__ void g2lds16(const void* g, void* l) {
  // async global->LDS, 16B/lane; LDS dest = wave-uniform base + lane*16
  __builtin_amdgcn_global_load_lds((gas_ptr)g, (las_ptr)l, 16, 0, 0);
}

__device__ __forceinline__ unsigned short bf16_rne(float f) {
  unsigned u = __builtin_bit_cast(unsigned, f);
  unsigned r = (u + 0x7FFFu + ((u >> 16) & 1u)) >> 16;
  return (unsigned short)r;
}
__device__ __forceinline__ float bf16_to_f(unsigned short h) {
  unsigned u = ((unsigned)h) << 16;
  return __builtin_bit_cast(float, u);
}

// Convert centroids fp32 -> bf16 hi/lo (row-major [512][64]) + ||c||^2.
__global__ void prep_kernel(const float* __restrict__ c,
                            unsigned short* __restrict__ ch,
                            unsigned short* __restrict__ cl,
                            float* __restrict__ csq) {
  int t = blockIdx.x * 256 + threadIdx.x;  // 0..4095
  int row = t >> 3, d0 = (t & 7) * 8;
  const float* cp = c + row * DDIM + d0;
  float4 v0 = *(const float4*)cp;
  float4 v1 = *(const float4*)(cp + 4);
  float xv[8] = {v0.x, v0.y, v0.z, v0.w, v1.x, v1.y, v1.z, v1.w};
  short8 hh, ll;
  float s = 0.f;
#pragma unroll
  for (int i = 0; i < 8; ++i) {
    unsigned short h = bf16_rne(xv[i]);
    hh[i] = (short)h;
    ll[i] = (short)bf16_rne(xv[i] - bf16_to_f(h));
    s = fmaf(xv[i], xv[i], s);
  }
  s += __shfl_xor(s, 1, 64);
  s += __shfl_xor(s, 2, 64);
  s += __shfl_xor(s, 4, 64);
  if ((t & 7) == 0) csq[row] = s;
  *(short8*)(ch + row * DDIM + d0) = hh;
  *(short8*)(cl + row * DDIM + d0) = ll;
}

__global__ __launch_bounds__(THREADS) void cluster_kernel(
    const float* __restrict__ xg,
    const unsigned short* __restrict__ chw,  // [512][64] bf16 hi
    const unsigned short* __restrict__ clw,  // [512][64] bf16 lo
    const float* __restrict__ csq,
    float* __restrict__ outg) {
  __shared__ __align__(16) char sBh[32768];  // 256-col chunk, hi, swizzled
  __shared__ __align__(16) char sBl[32768];  // lo
  __shared__ __align__(16) char sXh[4096];   // 32x64 bf16 hi, swizzled
  __shared__ __align__(16) char sXl[4096];
  __shared__ float sX1[BM];                  // 1 + ||x_r||^2
  __shared__ __align__(16) float sPart[BM][4];

  const int tid = threadIdx.x;
  const int lane = tid & 63;
  const int wv = tid >> 6;
  const int half = lane >> 5;
  const int l5 = lane & 31;
  const long rowBase = (long)blockIdx.x * BM;

  const char* gch = (const char*)chw;
  const char* gcl = (const char*)clw;

  // ---- issue chunk0 staging (cols 0..255): pre-swizzled global source ----
#pragma unroll
  for (int i = 0; i < 8; ++i) {
    int p = (i * THREADS + tid) * 16;
    int lg = p ^ (((p >> 7) & 7) << 4);
    g2lds16(gch + lg, sBh + p);
    g2lds16(gcl + lg, sBl + p);
  }

  // ---- load X tile, split to bf16 hi/lo, write LDS swizzled ----
  {
    int r = tid >> 3, d0 = (tid & 7) * 8;
    const float* xp = xg + (rowBase + r) * DDIM + d0;
    float4 v0 = *(const float4*)xp;
    float4 v1 = *(const float4*)(xp + 4);
    float xv[8] = {v0.x, v0.y, v0.z, v0.w, v1.x, v1.y, v1.z, v1.w};
    short8 hh, ll;
    float s = 0.f;
#pragma unroll
    for (int i = 0; i < 8; ++i) {
      unsigned short h = bf16_rne(xv[i]);
      hh[i] = (short)h;
      ll[i] = (short)bf16_rne(xv[i] - bf16_to_f(h));
      s = fmaf(xv[i], xv[i], s);
    }
    int byte = (r * 128 + d0 * 2) ^ ((r & 7) << 4);
    *(short8*)(sXh + byte) = hh;
    *(short8*)(sXl + byte) = ll;
    s += __shfl_xor(s, 1, 64);
    s += __shfl_xor(s, 2, 64);
    s += __shfl_xor(s, 4, 64);
    if ((tid & 7) == 0) sX1[r] = 1.f + s;
  }

  __syncthreads();  // X + chunk0 staged (barrier drains vmcnt)

  // ---- A fragments for all 4 k-steps (rows = l5, k-chunk by half) ----
  short8 ah[4], al[4];
#pragma unroll
  for (int kk = 0; kk < 4; ++kk) {
    int byte = (l5 * 128 + kk * 32 + half * 16) ^ ((l5 & 7) << 4);
    ah[kk] = *(const short8*)(sXh + byte);
    al[kk] = *(const short8*)(sXl + byte);
  }

  // ---- ||c||^2 for this thread's 4 tiles ----
  // tile(t) = (t>>1)*8 + wv + 4*(t&1); col = tile*32 + l5
  float c1[4];
#pragma unroll
  for (int t = 0; t < 4; ++t)
    c1[t] = csq[((t >> 1) * 8 + wv + 4 * (t & 1)) * 32 + l5];

  // ---- 1 + ||x||^2 per (reg, half) ----
  float x1v[16];
#pragma unroll
  for (int r = 0; r < 16; ++r)
    x1v[r] = sX1[(r & 3) + 8 * (r >> 2) + 4 * half];

  f32x16 acc[4];
#pragma unroll
  for (int i = 0; i < 4; ++i)
#pragma unroll
    for (int j = 0; j < 16; ++j) acc[i][j] = 0.f;

  const int sw = (l5 & 7) << 4;

#define COMPUTE_CHUNK(c)                                                      \
  _Pragma("unroll") for (int tt = 0; tt < 2; ++tt) {                          \
    const int ai = (c) * 2 + tt;                                              \
    const int bbase = ((wv + 4 * tt) * 32 + l5) * 128;                        \
    _Pragma("unroll") for (int kk = 0; kk < 4; ++kk) {                        \
      int byte = (bbase + kk * 32 + half * 16) ^ sw;                          \
      short8 bh = *(const short8*)(sBh + byte);                               \
      short8 bl = *(const short8*)(sBl + byte);                               \
      acc[ai] = __builtin_amdgcn_mfma_f32_32x32x16_bf16(ah[kk], bh, acc[ai],  \
                                                        0, 0, 0);             \
      acc[ai] = __builtin_amdgcn_mfma_f32_32x32x16_bf16(al[kk], bh, acc[ai],  \
                                                        0, 0, 0);             \
      acc[ai] = __builtin_amdgcn_mfma_f32_32x32x16_bf16(ah[kk], bl, acc[ai],  \
                                                        0, 0, 0);             \
    }                                                                         \
  }

#define QTRANSFORM(c)                                                         \
  _Pragma("unroll") for (int tt = 0; tt < 2; ++tt) {                          \
    const int ai = (c) * 2 + tt;                                              \
    _Pragma("unroll") for (int r = 0; r < 16; ++r) {                          \
      float tv = fmaf(-2.f, acc[ai][r], x1v[r] + c1[ai]);                     \
      acc[ai][r] = __builtin_amdgcn_rcpf(tv);                                 \
    }                                                                         \
  }

  COMPUTE_CHUNK(0)
  __syncthreads();  // all waves done reading chunk0 B

  // ---- issue chunk1 staging (cols 256..511) ----
#pragma unroll
  for (int i = 0; i < 8; ++i) {
    int p = (i * THREADS + tid) * 16;
    int lg = p ^ (((p >> 7) & 7) << 4);
    g2lds16(gch + 32768 + lg, sBh + p);
    g2lds16(gcl + 32768 + lg, sBl + p);
  }

  // overlap staging latency with chunk0 epilogue math
  QTRANSFORM(0)

  __syncthreads();  // chunk1 staged

  COMPUTE_CHUNK(1)
  QTRANSFORM(1)

  // ---- row sums: tiles -> lanes-in-half -> cross-wave via LDS ----
  float rs[16];
#pragma unroll
  for (int r = 0; r < 16; ++r) {
    float s = (acc[0][r] + acc[1][r]) + (acc[2][r] + acc[3][r]);
    s += __shfl_xor(s, 1, 64);
    s += __shfl_xor(s, 2, 64);
    s += __shfl_xor(s, 4, 64);
    s += __shfl_xor(s, 8, 64);
    s += __shfl_xor(s, 16, 64);
    rs[r] = s;
  }
#pragma unroll
  for (int r = 0; r < 16; ++r) {
    if (l5 == r) sPart[(r & 3) + 8 * (r >> 2) + 4 * half][wv] = rs[r];
  }
  __syncthreads();

  // ---- scale + store (128B contiguous per half-wave per store) ----
#pragma unroll
  for (int r = 0; r < 16; ++r) {
    int row = (r & 3) + 8 * (r >> 2) + 4 * half;
    float4 p = *(const float4*)&sPart[row][0];
    float inv = __builtin_amdgcn_rcpf((p.x + p.y) + (p.z + p.w));
    float* op = outg + (rowBase + row) * (long)KCL + l5;
#pragma unroll
    for (int t = 0; t < 4; ++t) {
      int tile = (t >> 1) * 8 + wv + 4 * (t & 1);
      op[tile * 32] = acc[t][r] * inv;
    }
  }
}

extern "C" void kernel_launch(void* const* d_in, const int* in_sizes, int n_in,
                              void* d_out, int out_size, void* d_ws, size_t ws_size,
                              hipStream_t stream) {
  const float* x = (const float*)d_in[0];
  const float* c = (const float*)d_in[1];
  float* out = (float*)d_out;

  unsigned short* ch = (unsigned short*)d_ws;                    // 64 KB
  unsigned short* cl = (unsigned short*)((char*)d_ws + 65536);   // 64 KB
  float* csq = (float*)((char*)d_ws + 131072);                   // 2 KB

  hipLaunchKernelGGL(prep_kernel, dim3(16), dim3(256), 0, stream, c, ch, cl, csq);
  hipLaunchKernelGGL(cluster_kernel, dim3(NROWS / BM), dim3(THREADS), 0, stream,
                     x, ch, cl, csq, out);
}